// Round 5
// baseline (106.212 us; speedup 1.0000x reference)
//
#include <hip/hip_runtime.h>
#include <math.h>

#define NTILES 64
#define TPC 8
#define NCLUST 8
#define GRID_SZ 16
#define DIM 512
#define DHID 128
#define NTOK 2048
#define LN_EPS 1e-5f
#define TB 16             // tokens per chunk
#define NCHUNK_MAX 192    // sum ceil(cnt/16) <= 2048/16 + 64 = 192

static __device__ __forceinline__ float fsign(float v) {
    return (v > 0.f) ? 1.f : ((v < 0.f) ? -1.f : 0.f);
}

// Partial column sums of Wd: grid (NTILES, 4), 512 threads, 32 dh rows each.
__global__ __launch_bounds__(512) void k_sig_part(const float* __restrict__ Wd,
                                                  float* __restrict__ psum) {
    int t = blockIdx.x, part = blockIdx.y, tid = threadIdx.x;
    const float* base = Wd + ((size_t)t * DHID + part * 32) * DIM + tid;
    float s = 0.f;
    #pragma unroll 8
    for (int j = 0; j < 32; ++j) s += base[(size_t)j * DIM];
    psum[((size_t)t * 4 + part) * DIM + tid] = s;
}

// tile_sigs + cluster_sigs + zero counts. grid (NCLUST), 512 threads.
__global__ __launch_bounds__(512) void k_csig(const float* __restrict__ psum,
                                              float* __restrict__ tile_sigs,
                                              float* __restrict__ cluster_sigs,
                                              int* __restrict__ counts) {
    int c = blockIdx.x, d = threadIdx.x;
    if (c == 0 && d < NTILES) counts[d] = 0;
    float csum = 0.f;
    #pragma unroll
    for (int k = 0; k < TPC; ++k) {
        int t = c * TPC + k;
        float s = psum[((size_t)t * 4 + 0) * DIM + d] + psum[((size_t)t * 4 + 1) * DIM + d]
                + psum[((size_t)t * 4 + 2) * DIM + d] + psum[((size_t)t * 4 + 3) * DIM + d];
        float sg = fsign(s);
        tile_sigs[(size_t)t * DIM + d] = sg;
        csum += sg;
    }
    cluster_sigs[(size_t)c * DIM + d] = fsign(csum);
}

// 4 waves per block, one token per wave: LayerNorm + routing + list build
__global__ __launch_bounds__(256) void k_ln_route(const float* __restrict__ x,
                                                  const float* __restrict__ gamma,
                                                  const float* __restrict__ beta,
                                                  const float* __restrict__ tile_sigs,
                                                  const float* __restrict__ cluster_sigs,
                                                  float* __restrict__ xn_out,
                                                  int* __restrict__ counts,
                                                  int* __restrict__ list) {
    int n = blockIdx.x * 4 + (threadIdx.x >> 6);
    int lane = threadIdx.x & 63;
    const float* xr = x + (size_t)n * DIM;

    float v[8];
    float sum = 0.f;
    #pragma unroll
    for (int j = 0; j < 8; ++j) { float t = xr[lane + 64 * j]; v[j] = t; sum += t; }
    #pragma unroll
    for (int off = 32; off; off >>= 1) sum += __shfl_xor(sum, off);
    float mu = sum * (1.f / DIM);

    float sq = 0.f;
    #pragma unroll
    for (int j = 0; j < 8; ++j) { float t = v[j] - mu; sq += t * t; }
    #pragma unroll
    for (int off = 32; off; off >>= 1) sq += __shfl_xor(sq, off);
    float rs = rsqrtf(sq * (1.f / DIM) + LN_EPS);

    float sg[8];
    #pragma unroll
    for (int j = 0; j < 8; ++j) {
        int d = lane + 64 * j;
        float xv = (v[j] - mu) * rs * gamma[d] + beta[d];
        xn_out[(size_t)n * DIM + d] = xv;
        sg[j] = fsign(xv);
    }

    // cluster argmax (scores exact integers in f32; strict > ascending = first-index tie-break)
    int best_c = 0; float best = -1e30f;
    for (int c = 0; c < NCLUST; ++c) {
        float s = 0.f;
        #pragma unroll
        for (int j = 0; j < 8; ++j) s += sg[j] * cluster_sigs[(size_t)c * DIM + lane + 64 * j];
        #pragma unroll
        for (int off = 32; off; off >>= 1) s += __shfl_xor(s, off);
        if (s > best) { best = s; best_c = c; }
    }
    int bt = best_c * TPC; float bts = -1e30f;
    for (int k = 0; k < TPC; ++k) {
        int t = best_c * TPC + k;
        float s = 0.f;
        #pragma unroll
        for (int j = 0; j < 8; ++j) s += sg[j] * tile_sigs[(size_t)t * DIM + lane + 64 * j];
        #pragma unroll
        for (int off = 32; off; off >>= 1) s += __shfl_xor(s, off);
        if (s > bts) { bts = s; bt = t; }
    }

    if (lane == 0) {
        int slot = atomicAdd(&counts[bt], 1);
        list[(size_t)bt * NTOK + slot] = n;
    }
}

// Build chunk descriptors: one wave. desc[i] = (tile<<16)|chunk_idx, -1 past end.
__global__ __launch_bounds__(64) void k_chunks(const int* __restrict__ counts,
                                               int* __restrict__ desc) {
    int lane = threadIdx.x;
    int nck = (counts[lane] + TB - 1) / TB;
    int pre = nck;
    #pragma unroll
    for (int off = 1; off < 64; off <<= 1) {
        int v = __shfl_up(pre, off);
        if (lane >= off) pre += v;
    }
    int total = __shfl(pre, 63);
    pre -= nck;
    for (int i = lane; i < NCHUNK_MAX; i += 64)
        if (i >= total) desc[i] = -1;
    for (int j = 0; j < nck; ++j)
        desc[pre + j] = (lane << 16) | j;
}

// Down-projection + spline. grid (NCHUNK_MAX, 4 dh-quarters), 512 threads.
// thread=(dh=tid>>4 in [0,32), q=tid&15): weight slice Wd[row][q*32..q*32+32) in 8 float4 regs.
__global__ __launch_bounds__(512) void k_down(const float* __restrict__ xn,
                                              const float* __restrict__ Wd,
                                              const float* __restrict__ sb,
                                              const float* __restrict__ ss,
                                              const int* __restrict__ counts,
                                              const int* __restrict__ list,
                                              const int* __restrict__ desc,
                                              float* __restrict__ hs) {
    int b = blockIdx.x;
    int dsc = desc[(b & 7) * (NCHUNK_MAX / 8) + (b >> 3)];  // same-tile chunks -> same XCD
    if (dsc < 0) return;
    int t = dsc >> 16;
    int base = (dsc & 0xffff) * TB;
    int m = min(TB, counts[t] - base);
    int qd = blockIdx.y;

    __shared__ float xn_s[TB][DIM];     // 32 KB
    __shared__ float h_s[TB][32];       // 2 KB
    __shared__ int toks[TB];

    int tid = threadIdx.x;
    int q = tid & 15;
    int dh = tid >> 4;                  // local row 0..31
    int row = t * DHID + qd * 32 + dh;

    // weights -> registers (one-time)
    float4 w[8];
    const float* wr = Wd + (size_t)row * DIM + q * 32;
    #pragma unroll
    for (int j = 0; j < 8; ++j) w[j] = *(const float4*)(wr + j * 4);

    if (tid < TB) toks[tid] = (tid < m) ? list[(size_t)t * NTOK + base + tid] : -1;

    // stage xn for TB tokens (zeros for padding): 4096 float4, 8 per thread
    #pragma unroll
    for (int k = 0; k < 8; ++k) {
        int f = tid + k * 512;
        int p = f >> 7;
        int d4 = (f & 127) * 4;
        int tok = (p < m) ? list[(size_t)t * NTOK + base + p] : -1;
        float4 v = {0.f, 0.f, 0.f, 0.f};
        if (tok >= 0) v = *(const float4*)(xn + (size_t)tok * DIM + d4);
        *(float4*)(&xn_s[p][d4]) = v;
    }
    __syncthreads();

    float acc[TB];
    #pragma unroll
    for (int p = 0; p < TB; ++p) acc[p] = 0.f;
    #pragma unroll
    for (int j = 0; j < 8; ++j) {
        float4 wj = w[j];
        #pragma unroll
        for (int p = 0; p < TB; ++p) {
            float4 xv = *(const float4*)(&xn_s[p][q * 32 + j * 4]);
            acc[p] += wj.x * xv.x + wj.y * xv.y + wj.z * xv.z + wj.w * xv.w;
        }
    }
    // butterfly over q (lane bits 0..3)
    #pragma unroll
    for (int p = 0; p < TB; ++p) {
        #pragma unroll
        for (int off = 1; off < 16; off <<= 1) acc[p] += __shfl_xor(acc[p], off);
    }
    if (q == 0) {
        #pragma unroll
        for (int p = 0; p < TB; ++p) h_s[p][dh] = acc[p];
    }
    __syncthreads();

    // spline: 512 elems (16 tok x 32 dh), one per thread
    {
        int p = tid >> 5, dd = tid & 31;
        if (p < m) {
            int dh_abs = qd * 32 + dd;
            float h = h_s[p][dd];
            float hn = 1.f / (1.f + expf(-h));
            float g = hn * (float)GRID_SZ;
            int idx = (int)g;
            idx = (idx > GRID_SZ - 1) ? GRID_SZ - 1 : (idx < 0 ? 0 : idx);
            float lp = g - (float)idx;
            float val = sb[((size_t)t * DHID + dh_abs) * GRID_SZ + idx]
                      + ss[((size_t)t * DHID + dh_abs) * GRID_SZ + idx] * lp;
            hs[(size_t)toks[p] * DHID + dh_abs] = val;
        }
    }
}

// Up-projection + residual. grid (NCHUNK_MAX, 4 d-quarters), 512 threads.
// thread=(du=tid>>2 in [0,128), s=tid&3): weight slice Wu[d][s*32..s*32+32) in 8 float4 regs.
__global__ __launch_bounds__(512) void k_up(const float* __restrict__ x,
                                            const float* __restrict__ hs,
                                            const float* __restrict__ Wu,
                                            const float* __restrict__ scale,
                                            const int* __restrict__ counts,
                                            const int* __restrict__ list,
                                            const int* __restrict__ desc,
                                            float* __restrict__ out) {
    int b = blockIdx.x;
    int dsc = desc[(b & 7) * (NCHUNK_MAX / 8) + (b >> 3)];
    if (dsc < 0) return;
    int t = dsc >> 16;
    int base = (dsc & 0xffff) * TB;
    int m = min(TB, counts[t] - base);
    int qu = blockIdx.y;

    __shared__ float hs_s[TB][DHID];    // 8 KB
    __shared__ float y_s[TB][128];      // 8 KB
    __shared__ int toks[TB];

    int tid = threadIdx.x;
    int s = tid & 3;
    int du = tid >> 2;                  // local output d 0..127
    int drow = t * DIM + qu * 128 + du;
    float sc_t = scale[t];

    float4 w[8];
    const float* wr = Wu + (size_t)drow * DHID + s * 32;
    #pragma unroll
    for (int j = 0; j < 8; ++j) w[j] = *(const float4*)(wr + j * 4);

    if (tid < TB) toks[tid] = (tid < m) ? list[(size_t)t * NTOK + base + tid] : -1;

    // stage hs for TB tokens: 512 float4, 1 per thread
    {
        int p = tid >> 5;
        int d4 = (tid & 31) * 4;
        int tok = (p < m) ? list[(size_t)t * NTOK + base + p] : -1;
        float4 v = {0.f, 0.f, 0.f, 0.f};
        if (tok >= 0) v = *(const float4*)(hs + (size_t)tok * DHID + d4);
        *(float4*)(&hs_s[p][d4]) = v;
    }
    __syncthreads();

    float acc[TB];
    #pragma unroll
    for (int p = 0; p < TB; ++p) acc[p] = 0.f;
    #pragma unroll
    for (int j = 0; j < 8; ++j) {
        float4 wj = w[j];
        #pragma unroll
        for (int p = 0; p < TB; ++p) {
            float4 hv = *(const float4*)(&hs_s[p][s * 32 + j * 4]);
            acc[p] += wj.x * hv.x + wj.y * hv.y + wj.z * hv.z + wj.w * hv.w;
        }
    }
    #pragma unroll
    for (int p = 0; p < TB; ++p) {
        acc[p] += __shfl_xor(acc[p], 1);
        acc[p] += __shfl_xor(acc[p], 2);
    }
    if (s == 0) {
        #pragma unroll
        for (int p = 0; p < TB; ++p) y_s[p][du] = acc[p];
    }
    __syncthreads();

    // residual + store: 2048 elems, 4 per thread, coalesced 512B runs
    #pragma unroll
    for (int k = 0; k < 4; ++k) {
        int f = tid + k * 512;
        int p = f >> 7, dd = f & 127;
        if (p < m) {
            int tok = toks[p];
            size_t o = (size_t)tok * DIM + qu * 128 + dd;
            out[o] = x[o] + y_s[p][dd] * sc_t;
        }
    }
}

extern "C" void kernel_launch(void* const* d_in, const int* in_sizes, int n_in,
                              void* d_out, int out_size, void* d_ws, size_t ws_size,
                              hipStream_t stream) {
    const float* x     = (const float*)d_in[0];
    const float* gamma = (const float*)d_in[1];
    const float* beta  = (const float*)d_in[2];
    const float* Wd    = (const float*)d_in[3];
    const float* sb    = (const float*)d_in[4];
    const float* ss    = (const float*)d_in[5];
    const float* Wu    = (const float*)d_in[6];
    const float* scale = (const float*)d_in[7];
    float* out = (float*)d_out;

    // workspace layout
    float* psum         = (float*)d_ws;                          // 64*4*512 f
    float* tile_sigs    = psum + (size_t)NTILES * 4 * DIM;       // 32K f
    float* cluster_sigs = tile_sigs + NTILES * DIM;              // 4K f
    float* xn           = cluster_sigs + NCLUST * DIM;           // 1M f
    int*   counts       = (int*)(xn + (size_t)NTOK * DIM);       // 64 ints
    int*   list         = counts + NTILES;                       // 128K ints
    int*   desc         = list + (size_t)NTILES * NTOK;          // 192 ints
    float* hs           = (float*)(desc + NCHUNK_MAX);           // 2048*128 f

    k_sig_part<<<dim3(NTILES, 4), 512, 0, stream>>>(Wd, psum);
    k_csig<<<NCLUST, 512, 0, stream>>>(psum, tile_sigs, cluster_sigs, counts);
    k_ln_route<<<NTOK / 4, 256, 0, stream>>>(x, gamma, beta, tile_sigs, cluster_sigs, xn, counts, list);
    k_chunks<<<1, 64, 0, stream>>>(counts, desc);
    k_down<<<dim3(NCHUNK_MAX, 4), 512, 0, stream>>>(xn, Wd, sb, ss, counts, list, desc, hs);
    k_up<<<dim3(NCHUNK_MAX, 4), 512, 0, stream>>>(x, hs, Wu, scale, counts, list, desc, out);
}

// Round 6
// 74.172 us; speedup vs baseline: 1.4320x; 1.4320x over previous
//
#include <hip/hip_runtime.h>
#include <math.h>

#define NTILES 64
#define TPC 8
#define NCLUST 8
#define GRID_SZ 16
#define DIM 512
#define DHID 128
#define NTOK 2048
#define LN_EPS 1e-5f
#define TB 16             // tokens per chunk
#define NCHUNK_MAX 192    // sum ceil(cnt/16) <= 2048/16 + 64 = 192

static __device__ __forceinline__ float fsign(float v) {
    return (v > 0.f) ? 1.f : ((v < 0.f) ? -1.f : 0.f);
}

// Partial column sums of Wd: grid (NTILES, 4), 512 threads, 32 dh rows each.
__global__ __launch_bounds__(512) void k_sig_part(const float* __restrict__ Wd,
                                                  float* __restrict__ psum) {
    int t = blockIdx.x, part = blockIdx.y, tid = threadIdx.x;
    const float* base = Wd + ((size_t)t * DHID + part * 32) * DIM + tid;
    float s = 0.f;
    #pragma unroll 8
    for (int j = 0; j < 32; ++j) s += base[(size_t)j * DIM];
    psum[((size_t)t * 4 + part) * DIM + tid] = s;
}

// tile_sigs + cluster_sigs + zero counts. grid (NCLUST), 512 threads.
__global__ __launch_bounds__(512) void k_csig(const float* __restrict__ psum,
                                              float* __restrict__ tile_sigs,
                                              float* __restrict__ cluster_sigs,
                                              int* __restrict__ counts) {
    int c = blockIdx.x, d = threadIdx.x;
    if (c == 0 && d < NTILES) counts[d] = 0;
    float csum = 0.f;
    #pragma unroll
    for (int k = 0; k < TPC; ++k) {
        int t = c * TPC + k;
        float s = psum[((size_t)t * 4 + 0) * DIM + d] + psum[((size_t)t * 4 + 1) * DIM + d]
                + psum[((size_t)t * 4 + 2) * DIM + d] + psum[((size_t)t * 4 + 3) * DIM + d];
        float sg = fsign(s);
        tile_sigs[(size_t)t * DIM + d] = sg;
        csum += sg;
    }
    cluster_sigs[(size_t)c * DIM + d] = fsign(csum);
}

// 4 waves per block, one token per wave: LayerNorm + routing + list build
__global__ __launch_bounds__(256) void k_ln_route(const float* __restrict__ x,
                                                  const float* __restrict__ gamma,
                                                  const float* __restrict__ beta,
                                                  const float* __restrict__ tile_sigs,
                                                  const float* __restrict__ cluster_sigs,
                                                  float* __restrict__ xn_out,
                                                  int* __restrict__ counts,
                                                  int* __restrict__ list) {
    int n = blockIdx.x * 4 + (threadIdx.x >> 6);
    int lane = threadIdx.x & 63;
    const float* xr = x + (size_t)n * DIM;

    float v[8];
    float sum = 0.f;
    #pragma unroll
    for (int j = 0; j < 8; ++j) { float t = xr[lane + 64 * j]; v[j] = t; sum += t; }
    #pragma unroll
    for (int off = 32; off; off >>= 1) sum += __shfl_xor(sum, off);
    float mu = sum * (1.f / DIM);

    float sq = 0.f;
    #pragma unroll
    for (int j = 0; j < 8; ++j) { float t = v[j] - mu; sq += t * t; }
    #pragma unroll
    for (int off = 32; off; off >>= 1) sq += __shfl_xor(sq, off);
    float rs = rsqrtf(sq * (1.f / DIM) + LN_EPS);

    float sg[8];
    #pragma unroll
    for (int j = 0; j < 8; ++j) {
        int d = lane + 64 * j;
        float xv = (v[j] - mu) * rs * gamma[d] + beta[d];
        xn_out[(size_t)n * DIM + d] = xv;
        sg[j] = fsign(xv);
    }

    // cluster argmax (scores exact integers in f32; strict > ascending = first-index tie-break)
    int best_c = 0; float best = -1e30f;
    for (int c = 0; c < NCLUST; ++c) {
        float s = 0.f;
        #pragma unroll
        for (int j = 0; j < 8; ++j) s += sg[j] * cluster_sigs[(size_t)c * DIM + lane + 64 * j];
        #pragma unroll
        for (int off = 32; off; off >>= 1) s += __shfl_xor(s, off);
        if (s > best) { best = s; best_c = c; }
    }
    int bt = best_c * TPC; float bts = -1e30f;
    for (int k = 0; k < TPC; ++k) {
        int t = best_c * TPC + k;
        float s = 0.f;
        #pragma unroll
        for (int j = 0; j < 8; ++j) s += sg[j] * tile_sigs[(size_t)t * DIM + lane + 64 * j];
        #pragma unroll
        for (int off = 32; off; off >>= 1) s += __shfl_xor(s, off);
        if (s > bts) { bts = s; bt = t; }
    }

    if (lane == 0) {
        int slot = atomicAdd(&counts[bt], 1);
        list[(size_t)bt * NTOK + slot] = n;
    }
}

// Build chunk descriptors: one wave. desc[i] = (tile<<16)|chunk_idx, -1 past end.
__global__ __launch_bounds__(64) void k_chunks(const int* __restrict__ counts,
                                               int* __restrict__ desc) {
    int lane = threadIdx.x;
    int nck = (counts[lane] + TB - 1) / TB;
    int pre = nck;
    #pragma unroll
    for (int off = 1; off < 64; off <<= 1) {
        int v = __shfl_up(pre, off);
        if (lane >= off) pre += v;
    }
    int total = __shfl(pre, 63);
    pre -= nck;
    for (int i = lane; i < NCHUNK_MAX; i += 64)
        if (i >= total) desc[i] = -1;
    for (int j = 0; j < nck; ++j)
        desc[pre + j] = (lane << 16) | j;
}

// Down-projection + spline. grid (NCHUNK_MAX, 4 dh-quarters), 512 threads.
// thread=(rp=tid>>5 owns rows 2rp,2rp+1; q=tid&31): d = q*4 + j*128, j=0..3.
// LDS reads: lanes q read contiguous 16B within 512B span -> conflict-free.
__global__ __launch_bounds__(512) void k_down(const float* __restrict__ xn,
                                              const float* __restrict__ Wd,
                                              const float* __restrict__ sb,
                                              const float* __restrict__ ss,
                                              const int* __restrict__ counts,
                                              const int* __restrict__ list,
                                              const int* __restrict__ desc,
                                              float* __restrict__ hs) {
    int b = blockIdx.x;
    int dsc = desc[(b & 7) * (NCHUNK_MAX / 8) + (b >> 3)];  // same-tile chunks -> same XCD
    if (dsc < 0) return;
    int t = dsc >> 16;
    int base = (dsc & 0xffff) * TB;
    int m = min(TB, counts[t] - base);
    int qd = blockIdx.y;

    __shared__ float xn_s[TB][DIM];     // 32 KB
    __shared__ float h_s[TB][32];       // 2 KB
    __shared__ int toks[TB];

    int tid = threadIdx.x;
    int q = tid & 31;
    int rp = tid >> 5;                  // 0..15 -> rows 2rp, 2rp+1
    int row0 = t * DHID + qd * 32 + 2 * rp;

    // weights -> registers (2 rows x 4 float4, interleaved slices)
    const float* wr0 = Wd + (size_t)row0 * DIM;
    float4 w0[4], w1[4];
    #pragma unroll
    for (int j = 0; j < 4; ++j) {
        w0[j] = *(const float4*)(wr0 + q * 4 + j * 128);
        w1[j] = *(const float4*)(wr0 + DIM + q * 4 + j * 128);
    }

    if (tid < TB) toks[tid] = (tid < m) ? list[(size_t)t * NTOK + base + tid] : -1;

    // stage xn for TB tokens (zeros for padding): 2048 float4, 4 per thread
    #pragma unroll
    for (int k = 0; k < 4; ++k) {
        int f = tid + k * 512;
        int p = f >> 7;
        int d4 = (f & 127) * 4;
        int tok = (p < m) ? list[(size_t)t * NTOK + base + p] : -1;
        float4 v = {0.f, 0.f, 0.f, 0.f};
        if (tok >= 0) v = *(const float4*)(xn + (size_t)tok * DIM + d4);
        *(float4*)(&xn_s[p][d4]) = v;
    }
    __syncthreads();

    float a0[TB], a1[TB];
    #pragma unroll
    for (int p = 0; p < TB; ++p) { a0[p] = 0.f; a1[p] = 0.f; }
    #pragma unroll
    for (int p = 0; p < TB; ++p) {
        #pragma unroll
        for (int j = 0; j < 4; ++j) {
            float4 xv = *(const float4*)(&xn_s[p][q * 4 + j * 128]);
            a0[p] += w0[j].x * xv.x + w0[j].y * xv.y + w0[j].z * xv.z + w0[j].w * xv.w;
            a1[p] += w1[j].x * xv.x + w1[j].y * xv.y + w1[j].z * xv.z + w1[j].w * xv.w;
        }
    }
    // butterfly over q (lane bits 0..4)
    #pragma unroll
    for (int p = 0; p < TB; ++p) {
        #pragma unroll
        for (int off = 1; off < 32; off <<= 1) {
            a0[p] += __shfl_xor(a0[p], off);
            a1[p] += __shfl_xor(a1[p], off);
        }
    }
    if (q == 0) {
        #pragma unroll
        for (int p = 0; p < TB; ++p) { h_s[p][2 * rp] = a0[p]; h_s[p][2 * rp + 1] = a1[p]; }
    }
    __syncthreads();

    // spline: 512 elems (16 tok x 32 dh), one per thread
    {
        int p = tid >> 5, dd = tid & 31;
        if (p < m) {
            int dh_abs = qd * 32 + dd;
            float h = h_s[p][dd];
            float hn = 1.f / (1.f + expf(-h));
            float g = hn * (float)GRID_SZ;
            int idx = (int)g;
            idx = (idx > GRID_SZ - 1) ? GRID_SZ - 1 : (idx < 0 ? 0 : idx);
            float lp = g - (float)idx;
            float val = sb[((size_t)t * DHID + dh_abs) * GRID_SZ + idx]
                      + ss[((size_t)t * DHID + dh_abs) * GRID_SZ + idx] * lp;
            hs[(size_t)toks[p] * DHID + dh_abs] = val;
        }
    }
}

// Up-projection + residual. grid (NCHUNK_MAX, 4 d-quarters), 512 threads.
// thread=(rp=tid>>3 owns output rows 2rp,2rp+1 of the 128-quarter; q=tid&7): dh = q*4 + j*32.
__global__ __launch_bounds__(512) void k_up(const float* __restrict__ x,
                                            const float* __restrict__ hs,
                                            const float* __restrict__ Wu,
                                            const float* __restrict__ scale,
                                            const int* __restrict__ counts,
                                            const int* __restrict__ list,
                                            const int* __restrict__ desc,
                                            float* __restrict__ out) {
    int b = blockIdx.x;
    int dsc = desc[(b & 7) * (NCHUNK_MAX / 8) + (b >> 3)];
    if (dsc < 0) return;
    int t = dsc >> 16;
    int base = (dsc & 0xffff) * TB;
    int m = min(TB, counts[t] - base);
    int qu = blockIdx.y;

    __shared__ float hs_s[TB][DHID];    // 8 KB
    __shared__ float y_s[TB][128];      // 8 KB
    __shared__ int toks[TB];

    int tid = threadIdx.x;
    int q = tid & 7;
    int rp = tid >> 3;                  // 0..63 -> local output rows 2rp, 2rp+1
    int drow0 = t * DIM + qu * 128 + 2 * rp;
    float sc_t = scale[t];

    const float* wr0 = Wu + (size_t)drow0 * DHID;
    float4 w0[4], w1[4];
    #pragma unroll
    for (int j = 0; j < 4; ++j) {
        w0[j] = *(const float4*)(wr0 + q * 4 + j * 32);
        w1[j] = *(const float4*)(wr0 + DHID + q * 4 + j * 32);
    }

    if (tid < TB) toks[tid] = (tid < m) ? list[(size_t)t * NTOK + base + tid] : -1;

    // stage hs for TB tokens: 512 float4, 1 per thread
    {
        int p = tid >> 5;
        int d4 = (tid & 31) * 4;
        int tok = (p < m) ? list[(size_t)t * NTOK + base + p] : -1;
        float4 v = {0.f, 0.f, 0.f, 0.f};
        if (tok >= 0) v = *(const float4*)(hs + (size_t)tok * DHID + d4);
        *(float4*)(&hs_s[p][d4]) = v;
    }
    __syncthreads();

    float a0[TB], a1[TB];
    #pragma unroll
    for (int p = 0; p < TB; ++p) { a0[p] = 0.f; a1[p] = 0.f; }
    #pragma unroll
    for (int p = 0; p < TB; ++p) {
        #pragma unroll
        for (int j = 0; j < 4; ++j) {
            float4 hv = *(const float4*)(&hs_s[p][q * 4 + j * 32]);
            a0[p] += w0[j].x * hv.x + w0[j].y * hv.y + w0[j].z * hv.z + w0[j].w * hv.w;
            a1[p] += w1[j].x * hv.x + w1[j].y * hv.y + w1[j].z * hv.z + w1[j].w * hv.w;
        }
    }
    #pragma unroll
    for (int p = 0; p < TB; ++p) {
        #pragma unroll
        for (int off = 1; off < 8; off <<= 1) {
            a0[p] += __shfl_xor(a0[p], off);
            a1[p] += __shfl_xor(a1[p], off);
        }
    }
    if (q == 0) {
        #pragma unroll
        for (int p = 0; p < TB; ++p) { y_s[p][2 * rp] = a0[p]; y_s[p][2 * rp + 1] = a1[p]; }
    }
    __syncthreads();

    // residual + store: 2048 elems, 4 per thread, coalesced 512B runs
    #pragma unroll
    for (int k = 0; k < 4; ++k) {
        int f = tid + k * 512;
        int p = f >> 7, dd = f & 127;
        if (p < m) {
            int tok = toks[p];
            size_t o = (size_t)tok * DIM + qu * 128 + dd;
            out[o] = x[o] + y_s[p][dd] * sc_t;
        }
    }
}

extern "C" void kernel_launch(void* const* d_in, const int* in_sizes, int n_in,
                              void* d_out, int out_size, void* d_ws, size_t ws_size,
                              hipStream_t stream) {
    const float* x     = (const float*)d_in[0];
    const float* gamma = (const float*)d_in[1];
    const float* beta  = (const float*)d_in[2];
    const float* Wd    = (const float*)d_in[3];
    const float* sb    = (const float*)d_in[4];
    const float* ss    = (const float*)d_in[5];
    const float* Wu    = (const float*)d_in[6];
    const float* scale = (const float*)d_in[7];
    float* out = (float*)d_out;

    // workspace layout
    float* psum         = (float*)d_ws;                          // 64*4*512 f
    float* tile_sigs    = psum + (size_t)NTILES * 4 * DIM;       // 32K f
    float* cluster_sigs = tile_sigs + NTILES * DIM;              // 4K f
    float* xn           = cluster_sigs + NCLUST * DIM;           // 1M f
    int*   counts       = (int*)(xn + (size_t)NTOK * DIM);       // 64 ints
    int*   list         = counts + NTILES;                       // 128K ints
    int*   desc         = list + (size_t)NTILES * NTOK;          // 192 ints
    float* hs           = (float*)(desc + NCHUNK_MAX);           // 2048*128 f

    k_sig_part<<<dim3(NTILES, 4), 512, 0, stream>>>(Wd, psum);
    k_csig<<<NCLUST, 512, 0, stream>>>(psum, tile_sigs, cluster_sigs, counts);
    k_ln_route<<<NTOK / 4, 256, 0, stream>>>(x, gamma, beta, tile_sigs, cluster_sigs, xn, counts, list);
    k_chunks<<<1, 64, 0, stream>>>(counts, desc);
    k_down<<<dim3(NCHUNK_MAX, 4), 512, 0, stream>>>(xn, Wd, sb, ss, counts, list, desc, hs);
    k_up<<<dim3(NCHUNK_MAX, 4), 512, 0, stream>>>(x, hs, Wu, scale, counts, list, desc, out);
}

// Round 7
// 59.840 us; speedup vs baseline: 1.7749x; 1.2395x over previous
//
#include <hip/hip_runtime.h>
#include <hip/hip_bf16.h>
#include <math.h>

#define NTILES 64
#define TPC 8
#define NCLUST 8
#define GRID_SZ 16
#define DIM 512
#define DHID 128
#define NTOK 2048
#define LN_EPS 1e-5f
#define TB 16             // tokens per chunk == MFMA M-tile
#define NCHUNK_MAX 192    // sum ceil(cnt/16) <= 128 + 60 < 192 = 8*24

typedef __attribute__((ext_vector_type(8))) short bf16x8;
typedef __attribute__((ext_vector_type(4))) float f32x4;

static __device__ __forceinline__ float fsign(float v) {
    return (v > 0.f) ? 1.f : ((v < 0.f) ? -1.f : 0.f);
}

// load 8 consecutive f32, convert to packed bf16x8 (RNE via __float2bfloat16)
static __device__ __forceinline__ bf16x8 cvt8(const float* p) {
    float4 a = *(const float4*)p;
    float4 b = *(const float4*)(p + 4);
    float e[8] = {a.x, a.y, a.z, a.w, b.x, b.y, b.z, b.w};
    bf16x8 v;
    #pragma unroll
    for (int i = 0; i < 8; ++i) {
        union { __hip_bfloat16 h; short s; } u;
        u.h = __float2bfloat16(e[i]);
        v[i] = u.s;
    }
    return v;
}

// Partial column sums of Wd: grid (NTILES, 8), 512 threads, 16 dh rows each.
__global__ __launch_bounds__(512) void k_sig_part(const float* __restrict__ Wd,
                                                  float* __restrict__ psum) {
    int t = blockIdx.x, part = blockIdx.y, tid = threadIdx.x;
    const float* base = Wd + ((size_t)t * DHID + part * 16) * DIM + tid;
    float s = 0.f;
    #pragma unroll
    for (int j = 0; j < 16; ++j) s += base[(size_t)j * DIM];
    psum[((size_t)t * 8 + part) * DIM + tid] = s;
}

// tile_sigs + cluster_sigs + zero counts. grid (NCLUST), 512 threads.
__global__ __launch_bounds__(512) void k_csig(const float* __restrict__ psum,
                                              float* __restrict__ tile_sigs,
                                              float* __restrict__ cluster_sigs,
                                              int* __restrict__ counts) {
    int c = blockIdx.x, d = threadIdx.x;
    if (c == 0 && d < NTILES) counts[d] = 0;
    float csum = 0.f;
    #pragma unroll
    for (int k = 0; k < TPC; ++k) {
        int t = c * TPC + k;
        float s = 0.f;
        #pragma unroll
        for (int p = 0; p < 8; ++p) s += psum[((size_t)t * 8 + p) * DIM + d];
        float sg = fsign(s);
        tile_sigs[(size_t)t * DIM + d] = sg;
        csum += sg;
    }
    cluster_sigs[(size_t)c * DIM + d] = fsign(csum);
}

// 4 waves per block, one token per wave: LayerNorm + routing + list build (exact fp32)
__global__ __launch_bounds__(256) void k_ln_route(const float* __restrict__ x,
                                                  const float* __restrict__ gamma,
                                                  const float* __restrict__ beta,
                                                  const float* __restrict__ tile_sigs,
                                                  const float* __restrict__ cluster_sigs,
                                                  float* __restrict__ xn_out,
                                                  int* __restrict__ counts,
                                                  int* __restrict__ list) {
    int n = blockIdx.x * 4 + (threadIdx.x >> 6);
    int lane = threadIdx.x & 63;
    const float* xr = x + (size_t)n * DIM;

    float v[8];
    float sum = 0.f;
    #pragma unroll
    for (int j = 0; j < 8; ++j) { float t = xr[lane + 64 * j]; v[j] = t; sum += t; }
    #pragma unroll
    for (int off = 32; off; off >>= 1) sum += __shfl_xor(sum, off);
    float mu = sum * (1.f / DIM);

    float sq = 0.f;
    #pragma unroll
    for (int j = 0; j < 8; ++j) { float t = v[j] - mu; sq += t * t; }
    #pragma unroll
    for (int off = 32; off; off >>= 1) sq += __shfl_xor(sq, off);
    float rs = rsqrtf(sq * (1.f / DIM) + LN_EPS);

    float sg[8];
    #pragma unroll
    for (int j = 0; j < 8; ++j) {
        int d = lane + 64 * j;
        float xv = (v[j] - mu) * rs * gamma[d] + beta[d];
        xn_out[(size_t)n * DIM + d] = xv;
        sg[j] = fsign(xv);
    }

    // cluster argmax (scores exact integers in f32; strict > ascending = first-index tie-break)
    int best_c = 0; float best = -1e30f;
    for (int c = 0; c < NCLUST; ++c) {
        float s = 0.f;
        #pragma unroll
        for (int j = 0; j < 8; ++j) s += sg[j] * cluster_sigs[(size_t)c * DIM + lane + 64 * j];
        #pragma unroll
        for (int off = 32; off; off >>= 1) s += __shfl_xor(s, off);
        if (s > best) { best = s; best_c = c; }
    }
    int bt = best_c * TPC; float bts = -1e30f;
    for (int k = 0; k < TPC; ++k) {
        int t = best_c * TPC + k;
        float s = 0.f;
        #pragma unroll
        for (int j = 0; j < 8; ++j) s += sg[j] * tile_sigs[(size_t)t * DIM + lane + 64 * j];
        #pragma unroll
        for (int off = 32; off; off >>= 1) s += __shfl_xor(s, off);
        if (s > bts) { bts = s; bt = t; }
    }

    if (lane == 0) {
        int slot = atomicAdd(&counts[bt], 1);
        list[(size_t)bt * NTOK + slot] = n;
    }
}

// Fused FFN, MFMA path. grid NCHUNK_MAX blocks x 256 threads (4 waves).
// Each block: self-route to a (tile, 16-token chunk) via in-wave scan of counts.
// down: C1[16 tok][128 dh] via 16x16x32 bf16 MFMA, wave w owns dh-tiles {2w,2w+1}.
// spline in-register on C1 fragments -> bf16 hs in 4KB XOR-swizzled LDS.
// up: C2[16 tok][512 d], wave w owns d-tiles {8w..8w+7}; fused scale+residual store.
__global__ __launch_bounds__(256) void k_ffn(const float* __restrict__ x,
                                             const float* __restrict__ xn,
                                             const float* __restrict__ Wd,
                                             const float* __restrict__ sb,
                                             const float* __restrict__ ss,
                                             const float* __restrict__ Wu,
                                             const float* __restrict__ scale,
                                             const int* __restrict__ counts,
                                             const int* __restrict__ list,
                                             float* __restrict__ out) {
    int tid = threadIdx.x;
    int lane = tid & 63;
    int wv = tid >> 6;

    // self-routing: chunk id with XCD-friendly remap (consecutive chunks -> same XCD)
    int cb = (blockIdx.x & 7) * (NCHUNK_MAX / 8) + (blockIdx.x >> 3);
    int cnt_l = counts[lane];
    int nck = (cnt_l + TB - 1) / TB;
    int pre = nck;
    #pragma unroll
    for (int off = 1; off < 64; off <<= 1) {
        int u = __shfl_up(pre, off);
        if (lane >= off) pre += u;
    }
    int total = __shfl(pre, 63);
    pre -= nck;                              // exclusive prefix
    if (cb >= total) return;
    unsigned long long msk = __ballot(cb >= pre && cb < pre + nck);
    int t = (int)__builtin_ctzll(msk);
    int base = (cb - __shfl(pre, t)) * TB;
    int m = min(TB, __shfl(cnt_l, t) - base);

    __shared__ int toks[TB];
    __shared__ __align__(16) unsigned short hsl[TB * DHID];   // bf16, XOR-swizzled

    if (tid < TB) toks[tid] = list[(size_t)t * NTOK + base + min(tid, m - 1)];
    __syncthreads();

    float sc_t = scale[t];
    int mrow = lane & 15;            // A: token slot; B: output column within 16-tile
    int ko = (lane >> 4) * 8;        // k-offset of this lane's 8 elems

    // ---------------- down ----------------
    const float* xrow = xn + (size_t)toks[mrow] * DIM;
    const float* wr0 = Wd + ((size_t)t * DHID + wv * 32 + mrow) * DIM;
    const float* wr1 = wr0 + (size_t)16 * DIM;
    f32x4 acc0 = {0.f, 0.f, 0.f, 0.f}, acc1 = acc0;
    #pragma unroll
    for (int kk = 0; kk < 16; ++kk) {
        int d = kk * 32 + ko;
        bf16x8 a = cvt8(xrow + d);
        acc0 = __builtin_amdgcn_mfma_f32_16x16x32_bf16(a, cvt8(wr0 + d), acc0, 0, 0, 0);
        acc1 = __builtin_amdgcn_mfma_f32_16x16x32_bf16(a, cvt8(wr1 + d), acc1, 0, 0, 0);
    }

    // spline on C1 fragments; write bf16 hs to swizzled LDS
    #pragma unroll
    for (int j = 0; j < 2; ++j) {
        f32x4 av = j ? acc1 : acc0;
        int dh = (2 * wv + j) * 16 + mrow;
        const float* sbt = sb + ((size_t)t * DHID + dh) * GRID_SZ;
        const float* sst = ss + ((size_t)t * DHID + dh) * GRID_SZ;
        #pragma unroll
        for (int r = 0; r < 4; ++r) {
            int tr = (lane >> 4) * 4 + r;        // token row
            float h = av[r];
            float hn = 1.f / (1.f + expf(-h));
            float g = hn * (float)GRID_SZ;
            int idx = (int)g;
            idx = idx > GRID_SZ - 1 ? GRID_SZ - 1 : idx;
            float lp = g - (float)idx;
            float val = sbt[idx] + sst[idx] * lp;
            union { __hip_bfloat16 h2; unsigned short s; } u;
            u.h2 = __float2bfloat16(val);
            hsl[(tr * DHID + dh) ^ ((tr & 7) << 3)] = u.s;
        }
    }
    __syncthreads();

    // ---------------- up ----------------
    bf16x8 a2[4];
    #pragma unroll
    for (int kk = 0; kk < 4; ++kk)
        a2[kk] = *(const bf16x8*)&hsl[(mrow * DHID + kk * 32 + ko) ^ ((mrow & 7) << 3)];

    #pragma unroll
    for (int nt = 0; nt < 8; ++nt) {
        int d = (wv * 8 + nt) * 16 + mrow;
        const float* wr = Wu + ((size_t)t * DIM + d) * DHID;
        f32x4 acc = {0.f, 0.f, 0.f, 0.f};
        #pragma unroll
        for (int kk = 0; kk < 4; ++kk)
            acc = __builtin_amdgcn_mfma_f32_16x16x32_bf16(a2[kk], cvt8(wr + kk * 32 + ko), acc, 0, 0, 0);
        #pragma unroll
        for (int r = 0; r < 4; ++r) {
            int tr = (lane >> 4) * 4 + r;
            if (tr < m) {
                size_t o = (size_t)toks[tr] * DIM + d;
                out[o] = x[o] + acc[r] * sc_t;
            }
        }
    }
}

extern "C" void kernel_launch(void* const* d_in, const int* in_sizes, int n_in,
                              void* d_out, int out_size, void* d_ws, size_t ws_size,
                              hipStream_t stream) {
    const float* x     = (const float*)d_in[0];
    const float* gamma = (const float*)d_in[1];
    const float* beta  = (const float*)d_in[2];
    const float* Wd    = (const float*)d_in[3];
    const float* sb    = (const float*)d_in[4];
    const float* ss    = (const float*)d_in[5];
    const float* Wu    = (const float*)d_in[6];
    const float* scale = (const float*)d_in[7];
    float* out = (float*)d_out;

    // workspace layout
    float* psum         = (float*)d_ws;                          // 64*8*512 f
    float* tile_sigs    = psum + (size_t)NTILES * 8 * DIM;       // 32K f
    float* cluster_sigs = tile_sigs + NTILES * DIM;              // 4K f
    float* xn           = cluster_sigs + NCLUST * DIM;           // 1M f
    int*   counts       = (int*)(xn + (size_t)NTOK * DIM);       // 64 ints
    int*   list         = counts + NTILES;                       // 128K ints

    k_sig_part<<<dim3(NTILES, 8), 512, 0, stream>>>(Wd, psum);
    k_csig<<<NCLUST, 512, 0, stream>>>(psum, tile_sigs, cluster_sigs, counts);
    k_ln_route<<<NTOK / 4, 256, 0, stream>>>(x, gamma, beta, tile_sigs, cluster_sigs, xn, counts, list);
    k_ffn<<<NCHUNK_MAX, 256, 0, stream>>>(x, xn, Wd, sb, ss, Wu, scale, counts, list, out);
}

// Round 8
// 52.805 us; speedup vs baseline: 2.0114x; 1.1332x over previous
//
#include <hip/hip_runtime.h>
#include <hip/hip_bf16.h>
#include <math.h>

#define NTILES 64
#define TPC 8
#define NCLUST 8
#define GRID_SZ 16
#define DIM 512
#define DHID 128
#define NTOK 2048
#define LN_EPS 1e-5f
#define TB 16             // tokens per chunk == MFMA M-tile
#define NCHUNK_MAX 192    // sum ceil(cnt/16) <= 128 + 60 < 192 = 8*24

typedef __attribute__((ext_vector_type(8))) short bf16x8;
typedef __attribute__((ext_vector_type(4))) float f32x4;

static __device__ __forceinline__ float fsign(float v) {
    return (v > 0.f) ? 1.f : ((v < 0.f) ? -1.f : 0.f);
}

// load 8 consecutive f32, convert to packed bf16x8 (RNE)
static __device__ __forceinline__ bf16x8 cvt8(const float* p) {
    float4 a = *(const float4*)p;
    float4 b = *(const float4*)(p + 4);
    float e[8] = {a.x, a.y, a.z, a.w, b.x, b.y, b.z, b.w};
    bf16x8 v;
    #pragma unroll
    for (int i = 0; i < 8; ++i) {
        union { __hip_bfloat16 h; short s; } u;
        u.h = __float2bfloat16(e[i]);
        v[i] = u.s;
    }
    return v;
}

static __device__ __forceinline__ unsigned short bf16bits(float f) {
    union { __hip_bfloat16 h; unsigned short s; } u;
    u.h = __float2bfloat16(f);
    return u.s;
}

// Partial column sums of Wd: grid (NTILES, 8), 512 threads, 16 dh rows each.
__global__ __launch_bounds__(512) void k_sig_part(const float* __restrict__ Wd,
                                                  float* __restrict__ psum) {
    int t = blockIdx.x, part = blockIdx.y, tid = threadIdx.x;
    const float* base = Wd + ((size_t)t * DHID + part * 16) * DIM + tid;
    float s = 0.f;
    #pragma unroll
    for (int j = 0; j < 16; ++j) s += base[(size_t)j * DIM];
    psum[((size_t)t * 8 + part) * DIM + tid] = s;
}

// tile_sigs + cluster_sigs + zero counts. grid (NCLUST), 512 threads.
__global__ __launch_bounds__(512) void k_csig(const float* __restrict__ psum,
                                              float* __restrict__ tile_sigs,
                                              float* __restrict__ cluster_sigs,
                                              int* __restrict__ counts) {
    int c = blockIdx.x, d = threadIdx.x;
    if (c == 0 && d < NTILES) counts[d] = 0;
    float csum = 0.f;
    #pragma unroll
    for (int k = 0; k < TPC; ++k) {
        int t = c * TPC + k;
        float s = 0.f;
        #pragma unroll
        for (int p = 0; p < 8; ++p) s += psum[((size_t)t * 8 + p) * DIM + d];
        float sg = fsign(s);
        tile_sigs[(size_t)t * DIM + d] = sg;
        csum += sg;
    }
    cluster_sigs[(size_t)c * DIM + d] = fsign(csum);
}

// 4 waves per block, one token per wave: LayerNorm (exact fp32 routing) + bf16 xn out
__global__ __launch_bounds__(256) void k_ln_route(const float* __restrict__ x,
                                                  const float* __restrict__ gamma,
                                                  const float* __restrict__ beta,
                                                  const float* __restrict__ tile_sigs,
                                                  const float* __restrict__ cluster_sigs,
                                                  unsigned short* __restrict__ xn_b,
                                                  int* __restrict__ counts,
                                                  int* __restrict__ list) {
    int n = blockIdx.x * 4 + (threadIdx.x >> 6);
    int lane = threadIdx.x & 63;
    const float* xr = x + (size_t)n * DIM;

    float v[8];
    float sum = 0.f;
    #pragma unroll
    for (int j = 0; j < 8; ++j) { float t = xr[lane + 64 * j]; v[j] = t; sum += t; }
    #pragma unroll
    for (int off = 32; off; off >>= 1) sum += __shfl_xor(sum, off);
    float mu = sum * (1.f / DIM);

    float sq = 0.f;
    #pragma unroll
    for (int j = 0; j < 8; ++j) { float t = v[j] - mu; sq += t * t; }
    #pragma unroll
    for (int off = 32; off; off >>= 1) sq += __shfl_xor(sq, off);
    float rs = rsqrtf(sq * (1.f / DIM) + LN_EPS);

    float sg[8];
    #pragma unroll
    for (int j = 0; j < 8; ++j) {
        int d = lane + 64 * j;
        float xv = (v[j] - mu) * rs * gamma[d] + beta[d];
        xn_b[(size_t)n * DIM + d] = bf16bits(xv);
        sg[j] = fsign(xv);
    }

    // cluster argmax (scores exact integers in f32; strict > ascending = first-index tie-break)
    int best_c = 0; float best = -1e30f;
    for (int c = 0; c < NCLUST; ++c) {
        float s = 0.f;
        #pragma unroll
        for (int j = 0; j < 8; ++j) s += sg[j] * cluster_sigs[(size_t)c * DIM + lane + 64 * j];
        #pragma unroll
        for (int off = 32; off; off >>= 1) s += __shfl_xor(s, off);
        if (s > best) { best = s; best_c = c; }
    }
    int bt = best_c * TPC; float bts = -1e30f;
    for (int k = 0; k < TPC; ++k) {
        int t = best_c * TPC + k;
        float s = 0.f;
        #pragma unroll
        for (int j = 0; j < 8; ++j) s += sg[j] * tile_sigs[(size_t)t * DIM + lane + 64 * j];
        #pragma unroll
        for (int off = 32; off; off >>= 1) s += __shfl_xor(s, off);
        if (s > bts) { bts = s; bt = t; }
    }

    if (lane == 0) {
        int slot = atomicAdd(&counts[bt], 1);
        list[(size_t)bt * NTOK + slot] = n;
    }
}

// in-wave self-routing: map chunk id cb -> (t, base, m). Returns false if no work.
static __device__ __forceinline__ bool route_chunk(const int* counts, int lane, int cb,
                                                   int& t, int& base, int& m) {
    int cnt_l = counts[lane];
    int nck = (cnt_l + TB - 1) / TB;
    int pre = nck;
    #pragma unroll
    for (int off = 1; off < 64; off <<= 1) {
        int u = __shfl_up(pre, off);
        if (lane >= off) pre += u;
    }
    int total = __shfl(pre, 63);
    pre -= nck;
    if (cb >= total) return false;
    unsigned long long msk = __ballot(cb >= pre && cb < pre + nck);
    t = (int)__builtin_ctzll(msk);
    base = (cb - __shfl(pre, t)) * TB;
    m = min(TB, __shfl(cnt_l, t) - base);
    return true;
}

// Down-projection + spline. grid (NCHUNK_MAX, 8 dh-tiles), 64 threads (1 wave).
// 16 MFMA (16x16x32) over K=512; spline on C fragments; bf16 hs -> global.
__global__ __launch_bounds__(64, 2) void k_down(const unsigned short* __restrict__ xn_b,
                                                const float* __restrict__ Wd,
                                                const float* __restrict__ sb,
                                                const float* __restrict__ ss,
                                                const int* __restrict__ counts,
                                                const int* __restrict__ list,
                                                unsigned short* __restrict__ hs_b) {
    int lane = threadIdx.x;
    int cb = ((int)blockIdx.x & 7) * (NCHUNK_MAX / 8) + ((int)blockIdx.x >> 3);
    int t, base, m;
    if (!route_chunk(counts, lane, cb, t, base, m)) return;
    int dt = blockIdx.y;

    int mrow = lane & 15;
    int ko = (lane >> 4) * 8;
    int tokm = list[(size_t)t * NTOK + base + min(mrow, m - 1)];

    const unsigned short* xr = xn_b + (size_t)tokm * DIM;
    const float* wr = Wd + ((size_t)t * DHID + dt * 16 + mrow) * DIM;

    f32x4 acc = {0.f, 0.f, 0.f, 0.f};
    #pragma unroll 8
    for (int kk = 0; kk < 16; ++kk) {
        int d = kk * 32 + ko;
        bf16x8 a = *(const bf16x8*)(xr + d);
        acc = __builtin_amdgcn_mfma_f32_16x16x32_bf16(a, cvt8(wr + d), acc, 0, 0, 0);
    }

    // spline: lane owns column dh = dt*16+mrow, rows (lane>>4)*4 + r
    int dh = dt * 16 + mrow;
    const float* sbt = sb + ((size_t)t * DHID + dh) * GRID_SZ;
    const float* sst = ss + ((size_t)t * DHID + dh) * GRID_SZ;
    #pragma unroll
    for (int r = 0; r < 4; ++r) {
        int tr = (lane >> 4) * 4 + r;
        float h = acc[r];
        float hn = 1.f / (1.f + expf(-h));
        float g = hn * (float)GRID_SZ;
        int idx = (int)g;
        idx = idx > GRID_SZ - 1 ? GRID_SZ - 1 : idx;
        float lp = g - (float)idx;
        float val = sbt[idx] + sst[idx] * lp;
        int tok_tr = __shfl(tokm, tr);
        if (tr < m) hs_b[(size_t)tok_tr * DHID + dh] = bf16bits(val);
    }
}

// Up-projection + residual. grid (NCHUNK_MAX, 8 d-slices of 64), 64 threads (1 wave).
// 16 MFMA (4 n-tiles x K=128); fused scale + residual store.
__global__ __launch_bounds__(64, 2) void k_up(const float* __restrict__ x,
                                              const unsigned short* __restrict__ hs_b,
                                              const float* __restrict__ Wu,
                                              const float* __restrict__ scale,
                                              const int* __restrict__ counts,
                                              const int* __restrict__ list,
                                              float* __restrict__ out) {
    int lane = threadIdx.x;
    int cb = ((int)blockIdx.x & 7) * (NCHUNK_MAX / 8) + ((int)blockIdx.x >> 3);
    int t, base, m;
    if (!route_chunk(counts, lane, cb, t, base, m)) return;
    int ds = blockIdx.y;

    int mrow = lane & 15;
    int ko = (lane >> 4) * 8;
    int tokm = list[(size_t)t * NTOK + base + min(mrow, m - 1)];
    float sc_t = scale[t];

    // A fragments: hs rows (bf16, 16B aligned)
    const unsigned short* hr = hs_b + (size_t)tokm * DHID;
    bf16x8 a2[4];
    #pragma unroll
    for (int kk = 0; kk < 4; ++kk)
        a2[kk] = *(const bf16x8*)(hr + kk * 32 + ko);

    #pragma unroll 2
    for (int nt = 0; nt < 4; ++nt) {
        int d = ds * 64 + nt * 16 + mrow;
        const float* wr = Wu + ((size_t)t * DIM + d) * DHID;
        f32x4 acc = {0.f, 0.f, 0.f, 0.f};
        #pragma unroll
        for (int kk = 0; kk < 4; ++kk)
            acc = __builtin_amdgcn_mfma_f32_16x16x32_bf16(a2[kk], cvt8(wr + kk * 32 + ko), acc, 0, 0, 0);
        #pragma unroll
        for (int r = 0; r < 4; ++r) {
            int tr = (lane >> 4) * 4 + r;
            int tok_tr = __shfl(tokm, tr);
            if (tr < m) {
                size_t o = (size_t)tok_tr * DIM + d;
                out[o] = x[o] + acc[r] * sc_t;
            }
        }
    }
}

extern "C" void kernel_launch(void* const* d_in, const int* in_sizes, int n_in,
                              void* d_out, int out_size, void* d_ws, size_t ws_size,
                              hipStream_t stream) {
    const float* x     = (const float*)d_in[0];
    const float* gamma = (const float*)d_in[1];
    const float* beta  = (const float*)d_in[2];
    const float* Wd    = (const float*)d_in[3];
    const float* sb    = (const float*)d_in[4];
    const float* ss    = (const float*)d_in[5];
    const float* Wu    = (const float*)d_in[6];
    const float* scale = (const float*)d_in[7];
    float* out = (float*)d_out;

    // workspace layout
    float* psum          = (float*)d_ws;                           // 64*8*512 f
    float* tile_sigs     = psum + (size_t)NTILES * 8 * DIM;        // 32K f
    float* cluster_sigs  = tile_sigs + NTILES * DIM;               // 4K f
    int*   counts        = (int*)(cluster_sigs + NCLUST * DIM);    // 64 ints
    int*   list          = counts + NTILES;                        // 128K ints
    unsigned short* xn_b = (unsigned short*)(list + (size_t)NTILES * NTOK);  // 1M u16
    unsigned short* hs_b = xn_b + (size_t)NTOK * DIM;              // 256K u16

    k_sig_part<<<dim3(NTILES, 8), 512, 0, stream>>>(Wd, psum);
    k_csig<<<NCLUST, 512, 0, stream>>>(psum, tile_sigs, cluster_sigs, counts);
    k_ln_route<<<NTOK / 4, 256, 0, stream>>>(x, gamma, beta, tile_sigs, cluster_sigs, xn_b, counts, list);
    k_down<<<dim3(NCHUNK_MAX, 8), 64, 0, stream>>>(xn_b, Wd, sb, ss, counts, list, hs_b);
    k_up<<<dim3(NCHUNK_MAX, 8), 64, 0, stream>>>(x, hs_b, Wu, scale, counts, list, out);
}